// Round 17
// baseline (172.134 us; speedup 1.0000x reference)
//
#include <hip/hip_runtime.h>
#include <hip/hip_bf16.h>

typedef __attribute__((ext_vector_type(8))) short short8;
typedef __attribute__((ext_vector_type(4))) float f32x4;

#define NTOK   100000
#define H      150
#define NKS    20          // K-steps of 32 (4 segs x 5)
#define BM     64          // token rows per block
#define NCHUNK 38          // ceil(BM*H*4 / 1024) 1KB DMA chunks
#define BUFB   (NCHUNK*1024)  // 38912 B per LDS buffer
#define OUTOFF (NTOK * H)
#define XLIM   ((long)NTOK * H * 4 - 16)   // last valid 16B-aligned src offset

__device__ __forceinline__ unsigned short f2bf(float f) {
    unsigned int u = __builtin_bit_cast(unsigned int, f);
    u = (u + 0x7FFFu + ((u >> 16) & 1u)) >> 16;   // RNE
    return (unsigned short)u;
}

// ---------------------------------------------------------------------------
// Prepass: pack weights FRAGMENT-MAJOR so every B-frag load in the main
// kernel is 64 lanes x 16B = 1KB fully contiguous.
// wb[(((n*NKS + ks)*64 + lane)*8 + j] = W_seg[k2][col]
//   seg = ks/5, s5 = ks%5, col = n*16 + (lane&15), k2 = s5*32 + (lane>>4)*8 + j
// ---------------------------------------------------------------------------
__global__ void prep_w(const float* __restrict__ w_in, const float* __restrict__ w_out,
                       const float* __restrict__ u_in, const float* __restrict__ u_out,
                       unsigned short* __restrict__ wb) {
    int idx = blockIdx.x * 256 + threadIdx.x;
    if (idx >= 10 * NKS * 64 * 8) return;        // 102400 elems
    int j    = idx & 7;
    int lane = (idx >> 3) & 63;
    int ks   = (idx >> 9) % NKS;
    int n    = idx / (512 * NKS);
    int seg  = ks / 5, s5 = ks % 5;
    int col  = n * 16 + (lane & 15);
    int k2   = s5 * 32 + (lane >> 4) * 8 + j;
    float v = 0.0f;
    if (col < H && k2 < H) {
        const float* W = (seg == 0) ? w_in : (seg == 1) ? w_out : (seg == 2) ? u_in : u_out;
        v = W[k2 * H + col];
    }
    wb[idx] = f2bf(v);
}

// ---------------------------------------------------------------------------
// Main fused kernel — r13 data path at 2x the waves (pure-TLP A/B).
// Block = 64 rows x 160 cols; 8 waves in 4M x 2N (each wave 16 rows x 80
// cols, acc[5]). 512 threads. LDS dbuf 77.8KB; 2 blocks/CU = 16 waves/CU.
// Per segment: {batch 25 B-frag loads -> issue next-segment DMA -> 5
// K-steps on regs+LDS -> barrier}. Identical staging bursts to r13.
// ---------------------------------------------------------------------------
__global__ __launch_bounds__(512, 4) void lstm_fused(
        const float* __restrict__ s_in, const float* __restrict__ s_out,
        const float* __restrict__ h_in, const float* __restrict__ h_out,
        const float* __restrict__ last_c, const unsigned short* __restrict__ wb,
        float* __restrict__ out) {
    __shared__ __align__(16) unsigned char Xr[2][BUFB];   // 77824 B -> 2 blocks/CU

    const int t     = threadIdx.x;
    const int lane  = t & 63;
    const int wid   = t >> 6;      // 0..7
    const int waveM = wid >> 1;    // 0..3 -> rows waveM*16 + [0,16)
    const int waveN = wid & 1;     // cols waveN*80 + [0,80)
    const int lrow  = lane & 15;   // A row in frag / B+C col in frag
    const int lko   = lane >> 4;   // k-group 0..3 / C row-group
    const int r0blk = blockIdx.x * BM;

    const float* Xseg[4] = {s_in, s_out, h_in, h_out};

    f32x4 acc[5];
#pragma unroll
    for (int n = 0; n < 5; n++) acc[n] = (f32x4){0.f, 0.f, 0.f, 0.f};

    // ---- DMA stage: 38 x 1KB chunks striped over 8 waves, zero VGPR cost ----
    auto stage = [&](int seg, int buf) {
        const char* base = (const char*)Xseg[seg];
        const long sofs = (long)r0blk * (H * 4);
        for (int c = wid; c < NCHUNK; c += 8) {
            long go = sofs + c * 1024 + lane * 16;
            if (go > XLIM) go = XLIM;              // tail-block clamp (valid floats)
            const void* gp = base + go;
            void* lp = &Xr[buf][c * 1024];         // wave-uniform dest
            __builtin_amdgcn_global_load_lds(
                (const __attribute__((address_space(1))) void*)gp,
                (__attribute__((address_space(3))) void*)lp, 16, 0, 0);
        }
    };

    stage(0, 0);
    __syncthreads();   // drains stage-0 DMA + sync

    for (int seg = 0; seg < 4; seg++) {
        // ---- 1) batch ALL 25 B-frag loads for this segment (L2-resident) ----
        short8 bseg[5][5];
#pragma unroll
        for (int s5 = 0; s5 < 5; s5++)
#pragma unroll
            for (int n = 0; n < 5; n++)
                bseg[s5][n] = *(const short8*)
                    &wb[((((long)waveN * 5 + n) * NKS + seg * 5 + s5) * 64 + lane) * 8];

        __builtin_amdgcn_sched_barrier(0);   // pin: B batch issued before DMA

        // ---- 2) issue next-segment DMA (back of the vmcnt FIFO) ----
        if (seg < 3) stage(seg + 1, (seg + 1) & 1);

        __builtin_amdgcn_sched_barrier(0);   // pin: DMA issued before compute

        // ---- 3) compute: 5 K-steps on registers + LDS only ----
        const float* Xf = (const float*)&Xr[seg & 1][0];   // [64][150] fp32
        const int row = waveM * 16 + lrow;
#pragma unroll
        for (int s5 = 0; s5 < 5; s5++) {
            const int k0 = s5 * 32 + lko * 8;
            const float* rp = Xf + row * H + k0;   // 8B-aligned
            float xv[8];
#pragma unroll
            for (int j = 0; j < 8; j += 2) {
                float2 v = *(const float2*)&rp[j];
                xv[j] = v.x; xv[j + 1] = v.y;
            }
            if (s5 == 4) {                          // mask k >= 150
#pragma unroll
                for (int j = 0; j < 8; j++)
                    xv[j] = (k0 + j < H) ? xv[j] : 0.f;
            }
            short8 af;
#pragma unroll
            for (int j = 0; j < 8; j++) af[j] = (short)f2bf(xv[j]);
#pragma unroll
            for (int n = 0; n < 5; n++)
                acc[n] = __builtin_amdgcn_mfma_f32_16x16x32_bf16(af, bseg[s5][n], acc[n], 0, 0, 0);
        }
        __syncthreads();   // next tile's DMA done; buffer reuse safe
    }

    // ---- fused epilogue: g=sigmoid(pre); cell=g*lc+g*g; hid=g*tanh(cell)
#pragma unroll
    for (int r = 0; r < 4; r++) {
        const int row = r0blk + waveM * 16 + lko * 4 + r;
        if (row >= NTOK) continue;
        const long rb = (long)row * H;
#pragma unroll
        for (int n = 0; n < 5; n++) {
            const int col = waveN * 80 + n * 16 + lrow;
            if (col >= H) continue;
            float pre = acc[n][r];
            float e   = __expf(-pre);
            float g   = __builtin_amdgcn_rcpf(1.f + e);
            float lc  = last_c[rb + col];
            float cell = g * lc + g * g;
            float e2  = __expf(-2.f * cell);
            float th  = (1.f - e2) * __builtin_amdgcn_rcpf(1.f + e2);
            out[rb + col]          = g * th;
            out[OUTOFF + rb + col] = cell;
        }
    }
}

extern "C" void kernel_launch(void* const* d_in, const int* in_sizes, int n_in,
                              void* d_out, int out_size, void* d_ws, size_t ws_size,
                              hipStream_t stream) {
    const float* s_in   = (const float*)d_in[0];
    const float* s_out  = (const float*)d_in[1];
    const float* h_in   = (const float*)d_in[2];
    const float* h_out  = (const float*)d_in[3];
    const float* last_c = (const float*)d_in[4];
    const float* w_in   = (const float*)d_in[5];
    const float* w_out  = (const float*)d_in[6];
    const float* u_in   = (const float*)d_in[7];
    const float* u_out  = (const float*)d_in[8];

    unsigned short* wb = (unsigned short*)d_ws;   // 102400*2 = 204800 B
    float* out = (float*)d_out;

    prep_w<<<(10 * NKS * 64 * 8 + 255) / 256, 256, 0, stream>>>(w_in, w_out, u_in, u_out, wb);

    const int nblocks = (NTOK + BM - 1) / BM;  // 1563 blocks, 8 waves (4Mx2N)
    lstm_fused<<<nblocks, 512, 0, stream>>>(s_in, s_out, h_in, h_out, last_c, wb, out);
}

// Round 18
// 122.156 us; speedup vs baseline: 1.4091x; 1.4091x over previous
//
#include <hip/hip_runtime.h>
#include <hip/hip_bf16.h>

typedef __attribute__((ext_vector_type(8))) short short8;
typedef __attribute__((ext_vector_type(4))) float f32x4;

#define NTOK   100000
#define H      150
#define NKS    20          // K-slabs; windows start at {0,32,64,96,120} floats
#define BM     64
#define LBUF   18432       // per-slab LDS: 8KB X (64x32 fp32 swz) + 10KB B
#define OUTOFF (NTOK * H)
#define AS1 __attribute__((address_space(1)))
#define AS3 __attribute__((address_space(3)))

__device__ __forceinline__ unsigned short f2bf(float f) {
    unsigned int u = __builtin_bit_cast(unsigned int, f);
    u = (u + 0x7FFFu + ((u >> 16) & 1u)) >> 16;   // RNE
    return (unsigned short)u;
}

template<int N> __device__ __forceinline__ void vwait() {
    if constexpr (N == 6)      asm volatile("s_waitcnt vmcnt(6)" ::: "memory");
    else if constexpr (N == 4) asm volatile("s_waitcnt vmcnt(4)" ::: "memory");
    else if constexpr (N == 3) asm volatile("s_waitcnt vmcnt(3)" ::: "memory");
    else if constexpr (N == 2) asm volatile("s_waitcnt vmcnt(2)" ::: "memory");
    else                       asm volatile("s_waitcnt vmcnt(0)" ::: "memory");
}

// ---------------------------------------------------------------------------
// Prepass: pack weights K-SLAB-major: wb[((ks*10 + n)*64 + lane)*8 + j].
// Window: s5<4 -> k2 = s5*32 + p; s5==4 -> k2 = 120 + p, with p<8 ZEROED
// (overlap with window 3) and k2>=150 zeroed (pad). p = (lane>>4)*8 + j.
// ---------------------------------------------------------------------------
__global__ void prep_w(const float* __restrict__ w_in, const float* __restrict__ w_out,
                       const float* __restrict__ u_in, const float* __restrict__ u_out,
                       unsigned short* __restrict__ wb) {
    int idx = blockIdx.x * 256 + threadIdx.x;
    if (idx >= NKS * 10 * 512) return;           // 102400 elems
    int j    = idx & 7;
    int lane = (idx >> 3) & 63;
    int n    = (idx >> 9) % 10;
    int ks   = idx / 5120;
    int seg  = ks / 5, s5 = ks % 5;
    int col  = n * 16 + (lane & 15);
    int p    = (lane >> 4) * 8 + j;
    int k2   = (s5 < 4) ? (s5 * 32 + p) : (120 + p);
    float v = 0.0f;
    if (col < H && k2 < H && !(s5 == 4 && p < 8)) {
        const float* W = (seg == 0) ? w_in : (seg == 1) ? w_out : (seg == 2) ? u_in : u_out;
        v = W[k2 * H + col];
    }
    wb[idx] = f2bf(v);
}

// ---------------------------------------------------------------------------
// Main fused kernel: K-slab LDS pipeline, zero VMEM in the compute phase.
// Block = 64 rows x 160 cols, 8 waves (4M x 2N), each 16 rows x 80 cols.
// 4-slot LDS ring (72KB -> 2 blocks/CU). Per iter:
//   vwait(2*c_w)  [slab ks landed, slabs ks+1,ks+2 stay in flight]
//   s_barrier     [all waves' chunks landed; frees ring slot (ks+3)%4]
//   stage(ks+3)   [3 DMA chunks/wave: 1 X + 1-2 B]
//   compute(ks)   [2 ds_read X (XOR-swz) + 8 cvt + 5 ds_read B + 5 MFMA]
// No vmcnt(0) mid-loop, no __syncthreads (raw barrier keeps DMA in flight).
// ---------------------------------------------------------------------------
__global__ __launch_bounds__(512, 4) void lstm_fused(
        const float* __restrict__ s_in, const float* __restrict__ s_out,
        const float* __restrict__ h_in, const float* __restrict__ h_out,
        const float* __restrict__ last_c, const unsigned short* __restrict__ wb,
        float* __restrict__ out) {
    __shared__ __align__(16) char lds[4 * LBUF];   // 73728 B

    const int t     = threadIdx.x;
    const int lane  = t & 63;
    const int wid   = t >> 6;       // 0..7
    const int waveM = wid >> 1;     // 0..3 -> rows waveM*16 + [0,16)
    const int waveN = wid & 1;      // cols waveN*80 + [0,80)
    const int lrow  = lane & 15;
    const int lko   = lane >> 4;
    const int r0blk = blockIdx.x * BM;
    const bool tail = (r0blk + BM > NTOK);
    const bool cw3  = (wid < 2);    // waves 0,1 stage 3 chunks/slab, others 2

    const float* Xseg[4] = {s_in, s_out, h_in, h_out};

    f32x4 acc[5];
#pragma unroll
    for (int n = 0; n < 5; n++) acc[n] = (f32x4){0.f, 0.f, 0.f, 0.f};

    // ---- stage one K-slab (X 8KB as 8 chunks, B 10KB as 10 chunks) ----
    auto stage = [&](int ks2) {
        char* lb = &lds[(ks2 & 3) * LBUF];
        const int s5 = ks2 % 5;
        const int sofs = (s5 < 4) ? s5 * 128 : 480;   // window byte offset (16B-aligned)
        // X chunk 'wid': tile rows wid*8 + (lane>>3), source piece XOR-swizzled
        {
            const char* xb = (const char*)Xseg[ks2 / 5];
            int rowg = r0blk + wid * 8 + (lane >> 3);
            if (rowg > NTOK - 1) rowg = NTOK - 1;
            const int q = (lane & 7) ^ ((lane >> 3) & 7);
            const long go = (long)rowg * 600 + sofs + q * 16;
            __builtin_amdgcn_global_load_lds(
                (const AS1 void*)(xb + go),
                (AS3 void*)(lb + wid * 1024 + lane * 16), 16, 0, 0);
        }
        // B chunks (contiguous 10KB slab in wb)
        {
            const char* bsrc = (const char*)wb + (long)ks2 * 10240;
            __builtin_amdgcn_global_load_lds(
                (const AS1 void*)(bsrc + wid * 1024 + lane * 16),
                (AS3 void*)(lb + 8192 + wid * 1024 + lane * 16), 16, 0, 0);
            if (cw3)
                __builtin_amdgcn_global_load_lds(
                    (const AS1 void*)(bsrc + (8 + wid) * 1024 + lane * 16),
                    (AS3 void*)(lb + 8192 + (8 + wid) * 1024 + lane * 16), 16, 0, 0);
        }
    };

    // ---- compute one K-slab: pure LDS + VALU + MFMA ----
    auto compute = [&](int ks2) {
        const char* lb = &lds[(ks2 & 3) * LBUF];
        const int row = waveM * 16 + lrow;
        const int r7 = lrow & 7;
        const char* xr = lb + row * 128;
        f32x4 v0 = *(const f32x4*)(xr + ((((lko << 1) | 0) ^ r7) << 4));
        f32x4 v1 = *(const f32x4*)(xr + ((((lko << 1) | 1) ^ r7) << 4));
        short8 af;
        af[0] = (short)f2bf(v0[0]); af[1] = (short)f2bf(v0[1]);
        af[2] = (short)f2bf(v0[2]); af[3] = (short)f2bf(v0[3]);
        af[4] = (short)f2bf(v1[0]); af[5] = (short)f2bf(v1[1]);
        af[6] = (short)f2bf(v1[2]); af[7] = (short)f2bf(v1[3]);
        const char* br = lb + 8192 + (waveN * 5) * 1024 + lane * 16;
#pragma unroll
        for (int n = 0; n < 5; n++) {
            short8 bf = *(const short8*)(br + n * 1024);
            acc[n] = __builtin_amdgcn_mfma_f32_16x16x32_bf16(af, bf, acc[n], 0, 0, 0);
        }
    };

    // ---- prologue: fill ring to depth 3 ----
    stage(0); stage(1); stage(2);

#pragma unroll
    for (int ks = 0; ks < NKS; ks++) {
        if (ks < NKS - 2)       { if (cw3) vwait<6>(); else vwait<4>(); }
        else if (ks == NKS - 2) { if (cw3) vwait<3>(); else vwait<2>(); }
        else                    vwait<0>();
        __builtin_amdgcn_s_barrier();
        asm volatile("" ::: "memory");   // no LDS-read hoisting above the barrier

        if (tail && (ks % 5) == 4) {
            // sanitize window-4 pad floats (150,151) of clamped rows: they were
            // DMA'd from past-array memory; zero them so NaN*0 can't occur.
            if (wid == 0 && lane < 33) {
                const int slot = 31 + lane;            // rows 99999 (clamped)
                const int r7s = slot & 7;
                *(float2*)&lds[(ks & 3) * LBUF + slot * 128 + ((7 ^ r7s) << 4) + 8]
                    = make_float2(0.f, 0.f);
            }
            asm volatile("s_waitcnt lgkmcnt(0)" ::: "memory");
            __builtin_amdgcn_s_barrier();
            asm volatile("" ::: "memory");
        }

        if (ks < NKS - 3) stage(ks + 3);
        compute(ks);
    }

    // ---- fused epilogue: g=sigmoid(pre); cell=g*lc+g*g; hid=g*tanh(cell)
#pragma unroll
    for (int r = 0; r < 4; r++) {
        const int row = r0blk + waveM * 16 + lko * 4 + r;
        if (row >= NTOK) continue;
        const long rb = (long)row * H;
#pragma unroll
        for (int n = 0; n < 5; n++) {
            const int col = waveN * 80 + n * 16 + lrow;
            if (col >= H) continue;
            float pre = acc[n][r];
            float e   = __expf(-pre);
            float g   = __builtin_amdgcn_rcpf(1.f + e);
            float lc  = last_c[rb + col];
            float cell = g * lc + g * g;
            float e2  = __expf(-2.f * cell);
            float th  = (1.f - e2) * __builtin_amdgcn_rcpf(1.f + e2);
            out[rb + col]          = g * th;
            out[OUTOFF + rb + col] = cell;
        }
    }
}

extern "C" void kernel_launch(void* const* d_in, const int* in_sizes, int n_in,
                              void* d_out, int out_size, void* d_ws, size_t ws_size,
                              hipStream_t stream) {
    const float* s_in   = (const float*)d_in[0];
    const float* s_out  = (const float*)d_in[1];
    const float* h_in   = (const float*)d_in[2];
    const float* h_out  = (const float*)d_in[3];
    const float* last_c = (const float*)d_in[4];
    const float* w_in   = (const float*)d_in[5];
    const float* w_out  = (const float*)d_in[6];
    const float* u_in   = (const float*)d_in[7];
    const float* u_out  = (const float*)d_in[8];

    unsigned short* wb = (unsigned short*)d_ws;   // 204800 B
    float* out = (float*)d_out;

    prep_w<<<(NKS * 10 * 512 + 255) / 256, 256, 0, stream>>>(w_in, w_out, u_in, u_out, wb);

    const int nblocks = (NTOK + BM - 1) / BM;  // 1563 blocks, 8 waves (4Mx2N)
    lstm_fused<<<nblocks, 512, 0, stream>>>(s_in, s_out, h_in, h_out, last_c, wb, out);
}

// Round 19
// 113.670 us; speedup vs baseline: 1.5143x; 1.0747x over previous
//
#include <hip/hip_runtime.h>
#include <hip/hip_bf16.h>

typedef __attribute__((ext_vector_type(8))) short short8;
typedef __attribute__((ext_vector_type(4))) float f32x4;

#define NTOK   100000
#define H      150
#define NKS    20          // K-slabs; float windows start {0,32,64,96,118} (all in-row)
#define BM     64
#define LBUF   18432       // per-slab LDS: 8KB X (64x32 fp32 swz) + 10KB B
#define OUTOFF (NTOK * H)
#define AS1 __attribute__((address_space(1)))
#define AS3 __attribute__((address_space(3)))

__device__ __forceinline__ unsigned short f2bf(float f) {
    unsigned int u = __builtin_bit_cast(unsigned int, f);
    u = (u + 0x7FFFu + ((u >> 16) & 1u)) >> 16;   // RNE
    return (unsigned short)u;
}

template<int N> __device__ __forceinline__ void vwait() {
    if constexpr (N == 6)       asm volatile("s_waitcnt vmcnt(6)" ::: "memory");
    else if constexpr (N == 4)  asm volatile("s_waitcnt vmcnt(4)" ::: "memory");
    else if constexpr (N == 23) asm volatile("s_waitcnt vmcnt(23)" ::: "memory");
    else if constexpr (N == 22) asm volatile("s_waitcnt vmcnt(22)" ::: "memory");
    else if constexpr (N == 20) asm volatile("s_waitcnt vmcnt(20)" ::: "memory");
    else                        asm volatile("s_waitcnt vmcnt(0)" ::: "memory");
}

// ---------------------------------------------------------------------------
// Prepass: pack weights K-SLAB-major: wb[((ks*10 + n)*64 + lane)*8 + j].
// Window: s5<4 -> k2 = s5*32 + p; s5==4 -> k2 = 118 + p (IN-ROW, bytes
// 472..599), with p<10 ZEROED (overlap with window 3). col>=150 zeroed.
// p = (lane>>4)*8 + j;  k2 <= 149 always -> no OOB anywhere on the X side.
// ---------------------------------------------------------------------------
__global__ void prep_w(const float* __restrict__ w_in, const float* __restrict__ w_out,
                       const float* __restrict__ u_in, const float* __restrict__ u_out,
                       unsigned short* __restrict__ wb) {
    int idx = blockIdx.x * 256 + threadIdx.x;
    if (idx >= NKS * 10 * 512) return;           // 102400 elems
    int j    = idx & 7;
    int lane = (idx >> 3) & 63;
    int n    = (idx >> 9) % 10;
    int ks   = idx / 5120;
    int seg  = ks / 5, s5 = ks % 5;
    int col  = n * 16 + (lane & 15);
    int p    = (lane >> 4) * 8 + j;
    int k2   = (s5 < 4) ? (s5 * 32 + p) : (118 + p);
    float v = 0.0f;
    if (col < H && !(s5 == 4 && p < 10)) {
        const float* W = (seg == 0) ? w_in : (seg == 1) ? w_out : (seg == 2) ? u_in : u_out;
        v = W[k2 * H + col];
    }
    wb[idx] = f2bf(v);
}

// ---------------------------------------------------------------------------
// Main fused kernel (r18 structure + lc-prefetch + in-row windows + setprio).
// Block = 64 rows x 160 cols, 8 waves (4M x 2N), each 16 rows x 80 cols.
// 4-slot LDS ring (72KB -> 2 blocks/CU). Per iter:
//   vwait(2*c_w) -> s_barrier -> stage(ks+3) -> compute(ks).
// ks==17: issue the 20 per-thread last_c loads (latency hides under the
// last 3 compute phases; FIFO-counted in the remaining vwaits).
// ---------------------------------------------------------------------------
__global__ __launch_bounds__(512, 4) void lstm_fused(
        const float* __restrict__ s_in, const float* __restrict__ s_out,
        const float* __restrict__ h_in, const float* __restrict__ h_out,
        const float* __restrict__ last_c, const unsigned short* __restrict__ wb,
        float* __restrict__ out) {
    __shared__ __align__(16) char lds[4 * LBUF];   // 73728 B

    const int t     = threadIdx.x;
    const int lane  = t & 63;
    const int wid   = t >> 6;       // 0..7
    const int waveM = wid >> 1;     // 0..3 -> rows waveM*16 + [0,16)
    const int waveN = wid & 1;      // cols waveN*80 + [0,80)
    const int lrow  = lane & 15;
    const int lko   = lane >> 4;
    const int r0blk = blockIdx.x * BM;
    const bool cw3  = (wid < 2);    // waves 0,1 stage 3 chunks/slab, others 2

    const float* Xseg[4] = {s_in, s_out, h_in, h_out};

    f32x4 acc[5];
#pragma unroll
    for (int n = 0; n < 5; n++) acc[n] = (f32x4){0.f, 0.f, 0.f, 0.f};

    float lcv[4][5];   // prefetched last_c values

    // ---- stage one K-slab (X 8KB as 8 chunks, B 10KB as 10 chunks) ----
    auto stage = [&](int ks2) {
        char* lb = &lds[(ks2 & 3) * LBUF];
        const int s5 = ks2 % 5;
        const int sofs = (s5 < 4) ? s5 * 128 : 472;   // window byte offset (in-row)
        // X chunk 'wid': tile rows wid*8 + (lane>>3), source piece XOR-swizzled
        {
            const char* xb = (const char*)Xseg[ks2 / 5];
            int rowg = r0blk + wid * 8 + (lane >> 3);
            if (rowg > NTOK - 1) rowg = NTOK - 1;     // tail block only; in-row reads
            const int q = (lane & 7) ^ ((lane >> 3) & 7);
            const long go = (long)rowg * 600 + sofs + q * 16;
            __builtin_amdgcn_global_load_lds(
                (const AS1 void*)(xb + go),
                (AS3 void*)(lb + wid * 1024 + lane * 16), 16, 0, 0);
        }
        // B chunks (contiguous 10KB slab in wb)
        {
            const char* bsrc = (const char*)wb + (long)ks2 * 10240;
            __builtin_amdgcn_global_load_lds(
                (const AS1 void*)(bsrc + wid * 1024 + lane * 16),
                (AS3 void*)(lb + 8192 + wid * 1024 + lane * 16), 16, 0, 0);
            if (cw3)
                __builtin_amdgcn_global_load_lds(
                    (const AS1 void*)(bsrc + (8 + wid) * 1024 + lane * 16),
                    (AS3 void*)(lb + 8192 + (8 + wid) * 1024 + lane * 16), 16, 0, 0);
        }
    };

    // ---- compute one K-slab: pure LDS + VALU + MFMA ----
    auto compute = [&](int ks2) {
        const char* lb = &lds[(ks2 & 3) * LBUF];
        const int row = waveM * 16 + lrow;
        const int r7 = lrow & 7;
        const char* xr = lb + row * 128;
        f32x4 v0 = *(const f32x4*)(xr + ((((lko << 1) | 0) ^ r7) << 4));
        f32x4 v1 = *(const f32x4*)(xr + ((((lko << 1) | 1) ^ r7) << 4));
        short8 af;
        af[0] = (short)f2bf(v0[0]); af[1] = (short)f2bf(v0[1]);
        af[2] = (short)f2bf(v0[2]); af[3] = (short)f2bf(v0[3]);
        af[4] = (short)f2bf(v1[0]); af[5] = (short)f2bf(v1[1]);
        af[6] = (short)f2bf(v1[2]); af[7] = (short)f2bf(v1[3]);
        const char* br = lb + 8192 + (waveN * 5) * 1024 + lane * 16;
        __builtin_amdgcn_s_setprio(1);
#pragma unroll
        for (int n = 0; n < 5; n++) {
            short8 bf = *(const short8*)(br + n * 1024);
            acc[n] = __builtin_amdgcn_mfma_f32_16x16x32_bf16(af, bf, acc[n], 0, 0, 0);
        }
        __builtin_amdgcn_s_setprio(0);
    };

    // ---- prologue: fill ring to depth 3 ----
    stage(0); stage(1); stage(2);

#pragma unroll
    for (int ks = 0; ks < NKS; ks++) {
        if (ks < NKS - 2)       { if (cw3) vwait<6>();  else vwait<4>();  }
        else if (ks == NKS - 2) { if (cw3) vwait<23>(); else vwait<22>(); }
        else                    vwait<20>();
        __builtin_amdgcn_s_barrier();
        asm volatile("" ::: "memory");   // no LDS-read hoisting above the barrier

        if (ks < NKS - 3) stage(ks + 3);

        if (ks == NKS - 3) {
            // prefetch last_c: 20 unconditional loads (clamped addrs -> exact
            // vmcnt count per wave); values for masked lanes unused.
#pragma unroll
            for (int r = 0; r < 4; r++) {
                int row = r0blk + waveM * 16 + lko * 4 + r;
                if (row > NTOK - 1) row = NTOK - 1;
#pragma unroll
                for (int n = 0; n < 5; n++) {
                    int col = waveN * 80 + n * 16 + lrow;
                    if (col >= H) col = 0;
                    lcv[r][n] = last_c[(long)row * H + col];
                }
            }
        }

        compute(ks);
    }

    vwait<0>();   // lc loads landed

    // ---- fused epilogue: g=sigmoid(pre); cell=g*lc+g*g; hid=g*tanh(cell)
#pragma unroll
    for (int r = 0; r < 4; r++) {
        const int row = r0blk + waveM * 16 + lko * 4 + r;
        if (row >= NTOK) continue;
        const long rb = (long)row * H;
#pragma unroll
        for (int n = 0; n < 5; n++) {
            const int col = waveN * 80 + n * 16 + lrow;
            if (col >= H) continue;
            float pre = acc[n][r];
            float e   = __expf(-pre);
            float g   = __builtin_amdgcn_rcpf(1.f + e);
            float cell = g * lcv[r][n] + g * g;
            float e2  = __expf(-2.f * cell);
            float th  = (1.f - e2) * __builtin_amdgcn_rcpf(1.f + e2);
            out[rb + col]          = g * th;
            out[OUTOFF + rb + col] = cell;
        }
    }
}

extern "C" void kernel_launch(void* const* d_in, const int* in_sizes, int n_in,
                              void* d_out, int out_size, void* d_ws, size_t ws_size,
                              hipStream_t stream) {
    const float* s_in   = (const float*)d_in[0];
    const float* s_out  = (const float*)d_in[1];
    const float* h_in   = (const float*)d_in[2];
    const float* h_out  = (const float*)d_in[3];
    const float* last_c = (const float*)d_in[4];
    const float* w_in   = (const float*)d_in[5];
    const float* w_out  = (const float*)d_in[6];
    const float* u_in   = (const float*)d_in[7];
    const float* u_out  = (const float*)d_in[8];

    unsigned short* wb = (unsigned short*)d_ws;   // 204800 B
    float* out = (float*)d_out;

    prep_w<<<(NKS * 10 * 512 + 255) / 256, 256, 0, stream>>>(w_in, w_out, u_in, u_out, wb);

    const int nblocks = (NTOK + BM - 1) / BM;  // 1563 blocks, 8 waves (4Mx2N)
    lstm_fused<<<nblocks, 512, 0, stream>>>(s_in, s_out, h_in, h_out, last_c, wb, out);
}